// Round 8
// baseline (513.443 us; speedup 1.0000x reference)
//
#include <hip/hip_runtime.h>
#include <math.h>

// BondOrderConv: out[e] = sigmoid( nf[src[e]]·W_src + b_src
//                                + nf[dst[e]]·W_dst + b_dst
//                                + ef[e]·W_edge + b_edge )
// F = 256 f32. Memory-bound: ~343 MB stream -> floor ~54.5 us @ 6.29 TB/s.
//
// Journal:
//  R2: 16 lanes/row x 4 rows, two kernels = 62.8 us.
//  R3: cooperative fused launch -> 726 GB/s streaming. NEVER.
//  R4: 8x8 layout -> 67.5 us (VGPR>64 occupancy cliff; many light waves win).
//  R5: persistent flag kernel = 484 us. Root cause: ALL-LANE device-scope
//      atomic polling (device-scope loads bypass XCD L2 -> ~1M serialized
//      far-atomics) + per-lane spin in fixup.
//  R6: two-kernel + prefetch/nt/__expf = 59.5 us (k2 ~95% of read ceiling).
//  R7: dots-fused + epilogue kernel B = 59.7 us (B's re-read+launch = k1 cost).
//  R8 (this): R5 structure, R5 bug fixed: lane-0-only relaxed poll +
//      __shfl broadcast (1 far-atomic per wave-iteration, ~100K total),
//      single __threadfence at ready-transition, defer-don't-spin main loop,
//      wave-local fixup from own XCD-L2-hot gdef range. All 2048 blocks
//      co-resident (launch_bounds(256,8), VGPR<=64).

#define FDIM 256
#define F4   64          // float4 per row

typedef float f32x4 __attribute__((ext_vector_type(4)));

__device__ __forceinline__ float dot4v(f32x4 a, f32x4 b) {
    return a[0] * b[0] + a[1] * b[1] + a[2] * b[2] + a[3] * b[3];
}

__global__ void __launch_bounds__(256, 8)
fused_flag_kernel(const float* __restrict__ nf, const float* __restrict__ ef,
                  const int* __restrict__ src, const int* __restrict__ dst,
                  const float* __restrict__ W_src, const float* __restrict__ b_src,
                  const float* __restrict__ W_dst, const float* __restrict__ b_dst,
                  const float* __restrict__ W_edge, const float* __restrict__ b_edge,
                  float* __restrict__ e_src, float* __restrict__ e_dst,
                  float* __restrict__ gdef, int* __restrict__ ctr,
                  float* __restrict__ out,
                  int n_nodes, int n_edges, int ng_node) {
    const int lane   = threadIdx.x & 63;
    const int sub    = lane >> 4;        // which of 4 rows in the unit
    const int i      = lane & 15;        // column lane within row
    const int wave   = (blockIdx.x * blockDim.x + threadIdx.x) >> 6;
    const int nwaves = (gridDim.x * blockDim.x) >> 6;

    const f32x4* We4 = reinterpret_cast<const f32x4*>(W_edge);
    const f32x4 w0 = We4[i], w1 = We4[i + 16], w2 = We4[i + 32], w3 = We4[i + 48];
    const float be = b_edge[0];

    const f32x4* ef4 = reinterpret_cast<const f32x4*>(ef);
    const int ngroups = (n_edges + 3) >> 2;

    // First edge group for this wave (node units peeled to waves < ng_node).
    const int g0 = (wave < ng_node) ? (wave + nwaves - ng_node) : (wave - ng_node);

    // Issue first edge group's loads BEFORE the node unit (hide node work).
    f32x4 x0, x1, x2, x3;
    const bool have_first = (g0 < ngroups);
    if (have_first) {
        const f32x4* row = ef4 + (size_t)(g0 * 4 + sub) * F4;
        x0 = __builtin_nontemporal_load(row + i);
        x1 = __builtin_nontemporal_load(row + i + 16);
        x2 = __builtin_nontemporal_load(row + i + 32);
        x3 = __builtin_nontemporal_load(row + i + 48);
    } else {
        x0 = x1 = x2 = x3 = (f32x4)0.f;
    }

    // ---- peeled node unit (producer; waves < ng_node only) ----
    if (wave < ng_node) {
        const int n = wave * 4 + sub;
        const f32x4* Ws4 = reinterpret_cast<const f32x4*>(W_src);
        const f32x4* Wd4 = reinterpret_cast<const f32x4*>(W_dst);
        const f32x4* row = reinterpret_cast<const f32x4*>(nf) + (size_t)n * F4;
        const f32x4 a0 = row[i], a1 = row[i + 16], a2 = row[i + 32], a3 = row[i + 48];
        float ss = dot4v(a0, Ws4[i])      + dot4v(a1, Ws4[i + 16])
                 + dot4v(a2, Ws4[i + 32]) + dot4v(a3, Ws4[i + 48]);
        float sd = dot4v(a0, Wd4[i])      + dot4v(a1, Wd4[i + 16])
                 + dot4v(a2, Wd4[i + 32]) + dot4v(a3, Wd4[i + 48]);
        #pragma unroll
        for (int off = 1; off < 16; off <<= 1) {
            ss += __shfl_xor(ss, off, 64);
            sd += __shfl_xor(sd, off, 64);
        }
        if (i == 0 && n < n_nodes) {
            e_src[n] = ss + b_src[0];
            e_dst[n] = sd + b_dst[0];
        }
        __threadfence();                      // release gate stores
        if (lane == 0) atomicAdd(ctr, 1);     // device-scope
    }

    if (!have_first) return;

    bool ready = false;
    int  k_ready = 0;   // edge iterations completed before gates were visible
    int  k = 0;
    int  g = g0;

    // ---- hot pipelined edge loop ----
    while (g < ngroups) {
        const int gn = g + nwaves;
        f32x4 y0, y1, y2, y3;
        if (gn < ngroups) {
            const f32x4* row = ef4 + (size_t)(gn * 4 + sub) * F4;
            y0 = __builtin_nontemporal_load(row + i);
            y1 = __builtin_nontemporal_load(row + i + 16);
            y2 = __builtin_nontemporal_load(row + i + 32);
            y3 = __builtin_nontemporal_load(row + i + 48);
        } else {
            y0 = y1 = y2 = y3 = (f32x4)0.f;
        }

        // Lane-0-only relaxed poll, broadcast; overlaps the prefetch loads.
        if (!ready) {
            int r = 0;
            if (lane == 0)
                r = __hip_atomic_load(ctr, __ATOMIC_RELAXED, __HIP_MEMORY_SCOPE_AGENT);
            r = __shfl(r, 0, 64);
            if (r >= ng_node) {
                __threadfence();              // acquire: gate stores visible
                ready = true;
                k_ready = k;
            }
        }

        float s = dot4v(x0, w0) + dot4v(x1, w1) + dot4v(x2, w2) + dot4v(x3, w3);
        #pragma unroll
        for (int off = 1; off < 16; off <<= 1) {
            s += __shfl_xor(s, off, 64);
        }
        const int e = g * 4 + sub;
        if (i == 0 && e < n_edges) {
            if (ready) {
                const float m = s + be + e_src[src[e]] + e_dst[dst[e]];
                out[e] = 1.0f / (1.0f + __expf(-m));
            } else {
                gdef[e] = s + be;             // defer; fix up below
            }
        }

        ++k;
        g = gn;
        x0 = y0; x1 = y1; x2 = y2; x3 = y3;
    }

    // ---- deferred fixup: iterations [0, k_ready), own gdef range (L2-hot) ----
    if (!ready) {                              // never saw the flag: wait now
        int r;
        do {
            if (lane == 0)
                r = __hip_atomic_load(ctr, __ATOMIC_RELAXED, __HIP_MEMORY_SCOPE_AGENT);
            r = __shfl(r, 0, 64);
            if (r < ng_node) __builtin_amdgcn_s_sleep(8);
        } while (r < ng_node);
        __threadfence();
        k_ready = k;
    }
    int gg = g0;
    for (int kk = 0; kk < k_ready; ++kk, gg += nwaves) {
        const int e = gg * 4 + sub;
        if (i == 0 && e < n_edges) {
            const float m = gdef[e] + e_src[src[e]] + e_dst[dst[e]];
            out[e] = 1.0f / (1.0f + __expf(-m));
        }
    }
}

extern "C" void kernel_launch(void* const* d_in, const int* in_sizes, int n_in,
                              void* d_out, int out_size, void* d_ws, size_t ws_size,
                              hipStream_t stream) {
    const float* node_feats = (const float*)d_in[0];
    const float* edge_feats = (const float*)d_in[1];
    const int*   src        = (const int*)d_in[2];
    const int*   dst        = (const int*)d_in[3];
    const float* W_src      = (const float*)d_in[4];
    const float* b_src      = (const float*)d_in[5];
    const float* W_dst      = (const float*)d_in[6];
    const float* b_dst      = (const float*)d_in[7];
    const float* W_edge     = (const float*)d_in[8];
    const float* b_edge     = (const float*)d_in[9];

    const int n_nodes = in_sizes[0] / FDIM;
    const int n_edges = in_sizes[2];
    const int ng_node = (n_nodes + 3) / 4;

    // ws layout: [ctr (4B) | pad to 256B | e_src | e_dst | gdef]
    int*   ctr   = (int*)d_ws;
    float* e_src = (float*)((char*)d_ws + 256);
    float* e_dst = e_src + n_nodes;
    float* gdef  = e_dst + n_nodes;

    // ctr must be 0 at every kernel start (ws not re-poisoned between replays).
    hipMemsetAsync(d_ws, 0, 4, stream);

    // 2048 blocks x 256 = 8192 waves, all co-resident (VGPR<=64 via bounds).
    fused_flag_kernel<<<2048, 256, 0, stream>>>(
        node_feats, edge_feats, src, dst,
        W_src, b_src, W_dst, b_dst, W_edge, b_edge,
        e_src, e_dst, gdef, ctr, (float*)d_out,
        n_nodes, n_edges, ng_node);
}

// Round 9
// 59.307 us; speedup vs baseline: 8.6573x; 8.6573x over previous
//
#include <hip/hip_runtime.h>
#include <math.h>

// BondOrderConv: out[e] = sigmoid( nf[src[e]]·W_src + b_src
//                                + nf[dst[e]]·W_dst + b_dst
//                                + ef[e]·W_edge + b_edge )
// F = 256 f32. Memory-bound: ~343 MB stream -> floor ~54.5 us @ 6.29 TB/s.
//
// Journal:
//  R2: 16 lanes/row x 4 rows, two kernels = 62.8 us.
//  R3: cooperative fused launch -> 726 GB/s streaming. NEVER.
//  R4: 8x8 layout -> 67.5 us (VGPR>64 occupancy cliff; many light waves win).
//  R5: persistent flag kernel (all-lane poll) = 484 us.
//  R6: two-kernel + prefetch/nt/__expf = 59.5 us (k2 ~95% of read ceiling).
//  R7: dots-fused + epilogue kernel B = 59.7 us (B's re-read+launch = k1 cost).
//  R8: lane-0-only poll = 513 us. FALSIFIES the R5 "all-lane" diagnosis:
//      ANY per-iteration poll of one global address by ~8K waves serializes
//      at the coherence point (replay with ~0 HBM fetch still took 500 us,
//      VALUBusy 2.8% @ 84% occupancy). NO global-flag polling on this chip.
//      Launch boundary is the only affordable sync here.
//  R9 (this): restore R6 (best known), k1 widened to one wave per node
//      (10000 waves vs 2500 -> better latency hiding on the 10.2 MB read).

#define FDIM 256
#define F4   64          // float4 per row

typedef float f32x4 __attribute__((ext_vector_type(4)));

__device__ __forceinline__ float dot4v(f32x4 a, f32x4 b) {
    return a[0] * b[0] + a[1] * b[1] + a[2] * b[2] + a[3] * b[3];
}

// Kernel 1: per-node gate scalars. One wave per node (64 lanes x 4 floats).
__global__ void node_gates_kernel(const float* __restrict__ nf,
                                  const float* __restrict__ W_src,
                                  const float* __restrict__ W_dst,
                                  const float* __restrict__ b_src,
                                  const float* __restrict__ b_dst,
                                  float* __restrict__ e_src,
                                  float* __restrict__ e_dst,
                                  int n_nodes) {
    const int lane   = threadIdx.x & 63;
    const int wave   = (blockIdx.x * blockDim.x + threadIdx.x) >> 6;
    const int nwaves = (gridDim.x * blockDim.x) >> 6;

    const f32x4 ws = reinterpret_cast<const f32x4*>(W_src)[lane];
    const f32x4 wd = reinterpret_cast<const f32x4*>(W_dst)[lane];
    const float bs = b_src[0];
    const float bd = b_dst[0];

    for (int n = wave; n < n_nodes; n += nwaves) {
        const f32x4 x = reinterpret_cast<const f32x4*>(nf)[(size_t)n * F4 + lane];
        float ss = dot4v(x, ws);
        float sd = dot4v(x, wd);
        #pragma unroll
        for (int off = 1; off < 64; off <<= 1) {
            ss += __shfl_xor(ss, off, 64);
            sd += __shfl_xor(sd, off, 64);
        }
        if (lane == 0) {
            e_src[n] = ss + bs;
            e_dst[n] = sd + bd;
        }
    }
}

// Kernel 2: per-edge gate + gather + sigmoid. 327 MB stream — the hot kernel.
// 16 lanes/row x 4 rows per wave-iteration, software-pipelined (next group's
// loads issue before current group's reduce/epilogue), nt loads, __expf.
__global__ void __launch_bounds__(256, 8)
edge_gate_kernel(const float* __restrict__ ef,
                 const int* __restrict__ src,
                 const int* __restrict__ dst,
                 const float* __restrict__ W_edge,
                 const float* __restrict__ b_edge,
                 const float* __restrict__ e_src,
                 const float* __restrict__ e_dst,
                 float* __restrict__ out,
                 int n_edges) {
    const int lane   = threadIdx.x & 63;
    const int sub    = lane >> 4;        // which of 4 edges
    const int i      = lane & 15;        // column lane within edge
    const int wave   = (blockIdx.x * blockDim.x + threadIdx.x) >> 6;
    const int nwaves = (gridDim.x * blockDim.x) >> 6;

    const f32x4* We4 = reinterpret_cast<const f32x4*>(W_edge);
    const f32x4 w0 = We4[i], w1 = We4[i + 16], w2 = We4[i + 32], w3 = We4[i + 48];
    const float be = b_edge[0];

    const f32x4* ef4 = reinterpret_cast<const f32x4*>(ef);
    const int ngroups = (n_edges + 3) >> 2;

    int g = wave;
    if (g >= ngroups) return;

    // Prologue: load group g.
    f32x4 x0, x1, x2, x3;
    {
        const int e = g * 4 + sub;
        if (e < n_edges) {
            const f32x4* row = ef4 + (size_t)e * F4;
            x0 = __builtin_nontemporal_load(row + i);
            x1 = __builtin_nontemporal_load(row + i + 16);
            x2 = __builtin_nontemporal_load(row + i + 32);
            x3 = __builtin_nontemporal_load(row + i + 48);
        } else {
            x0 = x1 = x2 = x3 = (f32x4)0.f;
        }
    }

    while (g < ngroups) {
        const int gn = g + nwaves;
        // Issue next group's loads EARLY — epilogue latency hides under them.
        f32x4 y0, y1, y2, y3;
        if (gn < ngroups) {
            const int en = gn * 4 + sub;
            if (en < n_edges) {
                const f32x4* row = ef4 + (size_t)en * F4;
                y0 = __builtin_nontemporal_load(row + i);
                y1 = __builtin_nontemporal_load(row + i + 16);
                y2 = __builtin_nontemporal_load(row + i + 32);
                y3 = __builtin_nontemporal_load(row + i + 48);
            } else {
                y0 = y1 = y2 = y3 = (f32x4)0.f;
            }
        }

        // Reduce current group.
        float s = dot4v(x0, w0) + dot4v(x1, w1) + dot4v(x2, w2) + dot4v(x3, w3);
        #pragma unroll
        for (int off = 1; off < 16; off <<= 1) {
            s += __shfl_xor(s, off, 64);
        }
        const int e = g * 4 + sub;
        if (i == 0 && e < n_edges) {
            const float m = s + be + e_src[src[e]] + e_dst[dst[e]];
            out[e] = 1.0f / (1.0f + __expf(-m));
        }

        g = gn;
        x0 = y0; x1 = y1; x2 = y2; x3 = y3;
    }
}

extern "C" void kernel_launch(void* const* d_in, const int* in_sizes, int n_in,
                              void* d_out, int out_size, void* d_ws, size_t ws_size,
                              hipStream_t stream) {
    const float* node_feats = (const float*)d_in[0];
    const float* edge_feats = (const float*)d_in[1];
    const int*   src        = (const int*)d_in[2];
    const int*   dst        = (const int*)d_in[3];
    const float* W_src      = (const float*)d_in[4];
    const float* b_src      = (const float*)d_in[5];
    const float* W_dst      = (const float*)d_in[6];
    const float* b_dst      = (const float*)d_in[7];
    const float* W_edge     = (const float*)d_in[8];
    const float* b_edge     = (const float*)d_in[9];

    const int n_nodes = in_sizes[0] / FDIM;
    const int n_edges = in_sizes[2];

    float* e_src = (float*)d_ws;
    float* e_dst = e_src + n_nodes;

    // Kernel 1: one wave per node -> 10000 waves -> 2500 blocks of 256.
    {
        int blocks = (n_nodes + 3) / 4;      // 4 waves per 256-thread block
        if (blocks > 2048) blocks = 2048;
        node_gates_kernel<<<blocks, 256, 0, stream>>>(
            node_feats, W_src, W_dst, b_src, b_dst, e_src, e_dst, n_nodes);
    }

    // Kernel 2: 80000 edge-groups over 8192 waves (~9.8 iterations each).
    {
        edge_gate_kernel<<<2048, 256, 0, stream>>>(
            edge_feats, src, dst, W_edge, b_edge, e_src, e_dst,
            (float*)d_out, n_edges);
    }
}